// Round 1
// baseline (2866.897 us; speedup 1.0000x reference)
//
#include <hip/hip_runtime.h>
#include <hip/hip_bf16.h>

// Problem constants
constexpr int kT  = 2048;   // tokens
constexpr int kH  = 2048;   // hidden
constexpr int kE  = 8;      // experts
constexpr int kI  = 4096;   // intermediate
constexpr int k2I = 8192;

typedef __attribute__((ext_vector_type(8))) short bf16x8;
typedef __attribute__((ext_vector_type(4))) float f32x4;

__device__ inline unsigned short f2bfu(float f) {
    __hip_bfloat16 h = __float2bfloat16(f);
    return *reinterpret_cast<unsigned short*>(&h);
}
__device__ inline unsigned pk2(float lo, float hi) {
    return (unsigned)f2bfu(lo) | ((unsigned)f2bfu(hi) << 16);
}

// async global->LDS, 16B per lane. LDS dest is wave-uniform base + lane*16.
__device__ inline void gload_lds16(const unsigned short* g, unsigned short* l) {
    __builtin_amdgcn_global_load_lds(
        (const __attribute__((address_space(1))) void*)g,
        (__attribute__((address_space(3))) void*)l, 16, 0, 0);
}

// ---------------------------------------------------------------------------
// Router: logits = x @ gate_w.T, then sparsemixer top-2 (scalar, E=8).
// One wave per token.
// ---------------------------------------------------------------------------
__global__ __launch_bounds__(256) void router_kernel(
    const float* __restrict__ x, const float* __restrict__ gw,
    float* __restrict__ gsel, int* __restrict__ sel, int* __restrict__ cnt)
{
    int t    = blockIdx.x * 4 + (threadIdx.x >> 6);
    int lane = threadIdx.x & 63;

    float acc[kE];
#pragma unroll
    for (int e = 0; e < kE; e++) acc[e] = 0.f;

    for (int h = lane; h < kH; h += 64) {
        float xv = x[(size_t)t * kH + h];
#pragma unroll
        for (int e = 0; e < kE; e++) acc[e] += xv * gw[e * kH + h];
    }
#pragma unroll
    for (int off = 32; off > 0; off >>= 1) {
#pragma unroll
        for (int e = 0; e < kE; e++) acc[e] += __shfl_down(acc[e], off, 64);
    }

    if (lane == 0) {
        float s[kE];
#pragma unroll
        for (int e = 0; e < kE; e++) s[e] = acc[e];

        float max1 = s[0]; int ind1 = 0;
        for (int e = 1; e < kE; e++) if (s[e] > max1) { max1 = s[e]; ind1 = e; }
        float denom1 = 0.f;
        for (int e = 0; e < kE; e++) {
            float factor = fmaxf(fabsf(s[e]), max1);
            bool mask = (max1 - s[e]) / factor > 0.02f;   // 2*JITTER_EPS
            if (!mask) denom1 += __expf(s[e] - max1);
        }
        float g1 = 1.f / denom1;

        float max2 = -__builtin_inff(); int ind2 = 0;
        for (int e = 0; e < kE; e++)
            if (e != ind1 && s[e] > max2) { max2 = s[e]; ind2 = e; }
        float denom2 = 0.f;
        for (int e = 0; e < kE; e++) {
            if (e == ind1) continue;
            float factor = fmaxf(fabsf(s[e]), max2);
            bool mask = (max2 - s[e]) / factor > 0.02f;
            if (!mask) denom2 += __expf(s[e] - max2);
        }
        float g2 = 1.f / denom2;

        gsel[t * 2]     = g1;
        gsel[t * 2 + 1] = g2;
        sel[t * 2]      = ind1;
        sel[t * 2 + 1]  = ind2;
        atomicAdd(&cnt[ind1], 1);
        atomicAdd(&cnt[ind2], 1);
    }
}

// ---------------------------------------------------------------------------
__global__ void offsets_kernel(const int* __restrict__ cnt, int* __restrict__ offs)
{
    if (threadIdx.x == 0) {
        int o = 0;
        for (int e = 0; e < kE; e++) { offs[e] = o; o += cnt[e]; }
    }
}

__global__ __launch_bounds__(256) void scatter_kernel(
    const float* __restrict__ gsel, const int* __restrict__ sel,
    const int* __restrict__ offs, int* __restrict__ cnt2,
    int* __restrict__ rowtok, int* __restrict__ pairid, float* __restrict__ gwr)
{
    int p = blockIdx.x * 256 + threadIdx.x;
    if (p >= kT * 2) return;
    int e   = sel[p];
    int pos = offs[e] + atomicAdd(&cnt2[e], 1);
    rowtok[pos] = p >> 1;
    pairid[pos] = p;
    gwr[pos]    = gsel[p];
}

__global__ __launch_bounds__(256) void gather_kernel(
    const float* __restrict__ x, const int* __restrict__ rowtok,
    unsigned short* __restrict__ Xg)
{
    int r = blockIdx.x;
    int t = rowtok[r];
    int c = threadIdx.x * 8;
    const float4* src = (const float4*)(x + (size_t)t * kH + c);
    float4 a = src[0], b = src[1];
    uint4 v = make_uint4(pk2(a.x, a.y), pk2(a.z, a.w), pk2(b.x, b.y), pk2(b.z, b.w));
    *(uint4*)(Xg + (size_t)r * kH + c) = v;
}

// ---------------------------------------------------------------------------
// Weight pre-conversion fp32 -> bf16 (memory-bound, grid-stride).
// ---------------------------------------------------------------------------
__global__ __launch_bounds__(256) void cvt_kernel(
    const float* __restrict__ src, unsigned short* __restrict__ dst, size_t n8)
{
    size_t i      = (size_t)blockIdx.x * 256 + threadIdx.x;
    size_t stride = (size_t)gridDim.x * 256;
    for (; i < n8; i += stride) {
        const float4* s = (const float4*)(src + i * 8);
        float4 a = s[0], b = s[1];
        *(uint4*)(dst + i * 8) =
            make_uint4(pk2(a.x, a.y), pk2(a.z, a.w), pk2(b.x, b.y), pk2(b.z, b.w));
    }
}

// ---------------------------------------------------------------------------
// GEMM1 (fast path): 128 rows x 64 n-pairs (128 MFMA cols: 64 gate + 64 up).
// m97 structure: BK=32, linear LDS, global_load_lds x4 per iter, 2 barriers.
// Each of 4 waves computes 32 rows x 128 cols (acc[2][8] f32x4).
// ---------------------------------------------------------------------------
__global__ __launch_bounds__(256) void gemm1_big(
    const unsigned short* __restrict__ wsb, const unsigned short* __restrict__ Xg,
    unsigned short* __restrict__ inter,
    const int* __restrict__ cnt, const int* __restrict__ offs)
{
    int e     = blockIdx.z;
    int count = cnt[e];
    int mt    = blockIdx.x;
    if (mt * 128 >= count) return;
    int nt      = blockIdx.y;
    int rowbase = offs[e] + mt * 128;
    int n0      = nt * 64;

    __shared__ unsigned short As[128 * 32];   // [128 rows][32 k] linear
    __shared__ unsigned short Bs[128 * 32];   // rows 0..63 gate, 64..127 up

    int tid = threadIdx.x, wave = tid >> 6, lane = tid & 63;

    f32x4 acc[2][8];
#pragma unroll
    for (int r = 0; r < 2; r++)
#pragma unroll
        for (int c = 0; c < 8; c++) acc[r][c] = {0.f, 0.f, 0.f, 0.f};

    const unsigned short* wsEb = wsb + (size_t)e * k2I * kH;

    // staging geometry: per call, lane l -> LDS row (wave*16 + l/4), col (l%4)*8
    int rS = wave * 16 + (lane >> 2);
    int cS = (lane & 3) * 8;
    const unsigned short* ag0 = Xg   + (size_t)(rowbase + rS) * kH + cS;
    const unsigned short* ag1 = ag0 + (size_t)64 * kH;
    const unsigned short* bg0 = wsEb + (size_t)(n0 + rS) * kH + cS;          // gate
    const unsigned short* bg1 = wsEb + (size_t)(kI + n0 + rS) * kH + cS;     // up
    unsigned short* lA = As + wave * 512;
    unsigned short* lB = Bs + wave * 512;

    int lrow = lane & 15, kch = (lane >> 4) * 8;

    for (int k0 = 0; k0 < kH; k0 += 32) {
        gload_lds16(ag0 + k0, lA);
        gload_lds16(ag1 + k0, lA + 2048);
        gload_lds16(bg0 + k0, lB);
        gload_lds16(bg1 + k0, lB + 2048);
        __syncthreads();   // compiler drains vmcnt(0) before s_barrier
        bf16x8 a0 = *(const bf16x8*)(&As[(wave * 32 + lrow) * 32 + kch]);
        bf16x8 a1 = *(const bf16x8*)(&As[(wave * 32 + 16 + lrow) * 32 + kch]);
#pragma unroll
        for (int ct = 0; ct < 8; ct++) {
            bf16x8 bv = *(const bf16x8*)(&Bs[(ct * 16 + lrow) * 32 + kch]);
            acc[0][ct] = __builtin_amdgcn_mfma_f32_16x16x32_bf16(a0, bv, acc[0][ct], 0, 0, 0);
            acc[1][ct] = __builtin_amdgcn_mfma_f32_16x16x32_bf16(a1, bv, acc[1][ct], 0, 0, 0);
        }
        __syncthreads();   // protect LDS before next iter's staging
    }

    int col16 = lane & 15;
#pragma unroll
    for (int rf = 0; rf < 2; rf++) {
#pragma unroll
        for (int ct = 0; ct < 4; ct++) {
#pragma unroll
            for (int ri = 0; ri < 4; ri++) {
                int lr = wave * 32 + rf * 16 + (lane >> 4) * 4 + ri;
                if (mt * 128 + lr < count) {
                    float g = acc[rf][ct][ri];
                    float u = acc[rf][ct + 4][ri];
                    float v = (g / (1.f + __expf(-g))) * u;   // silu(g)*u
                    inter[(size_t)(rowbase + lr) * kI + (n0 + ct * 16 + col16)] = f2bfu(v);
                }
            }
        }
    }
}

// ---------------------------------------------------------------------------
// GEMM2 (fast path): 128 rows x 128 h-cols, K = kI, same structure.
// ---------------------------------------------------------------------------
__global__ __launch_bounds__(256) void gemm2_big(
    const unsigned short* __restrict__ w2b, const unsigned short* __restrict__ inter,
    const int* __restrict__ cnt, const int* __restrict__ offs,
    const int* __restrict__ pairid, const float* __restrict__ gwr,
    float* __restrict__ outp)
{
    int e     = blockIdx.z;
    int count = cnt[e];
    int mt    = blockIdx.x;
    if (mt * 128 >= count) return;
    int nt      = blockIdx.y;
    int rowbase = offs[e] + mt * 128;
    int n0      = nt * 128;

    __shared__ unsigned short As[128 * 32];
    __shared__ unsigned short Bs[128 * 32];

    int tid = threadIdx.x, wave = tid >> 6, lane = tid & 63;

    f32x4 acc[2][8];
#pragma unroll
    for (int r = 0; r < 2; r++)
#pragma unroll
        for (int c = 0; c < 8; c++) acc[r][c] = {0.f, 0.f, 0.f, 0.f};

    const unsigned short* w2Eb = w2b + (size_t)e * kH * kI;

    int rS = wave * 16 + (lane >> 2);
    int cS = (lane & 3) * 8;
    const unsigned short* ag0 = inter + (size_t)(rowbase + rS) * kI + cS;
    const unsigned short* ag1 = ag0 + (size_t)64 * kI;
    const unsigned short* bg0 = w2Eb + (size_t)(n0 + rS) * kI + cS;
    const unsigned short* bg1 = w2Eb + (size_t)(n0 + 64 + rS) * kI + cS;
    unsigned short* lA = As + wave * 512;
    unsigned short* lB = Bs + wave * 512;

    int lrow = lane & 15, kch = (lane >> 4) * 8;

    for (int k0 = 0; k0 < kI; k0 += 32) {
        gload_lds16(ag0 + k0, lA);
        gload_lds16(ag1 + k0, lA + 2048);
        gload_lds16(bg0 + k0, lB);
        gload_lds16(bg1 + k0, lB + 2048);
        __syncthreads();
        bf16x8 a0 = *(const bf16x8*)(&As[(wave * 32 + lrow) * 32 + kch]);
        bf16x8 a1 = *(const bf16x8*)(&As[(wave * 32 + 16 + lrow) * 32 + kch]);
#pragma unroll
        for (int ct = 0; ct < 8; ct++) {
            bf16x8 bv = *(const bf16x8*)(&Bs[(ct * 16 + lrow) * 32 + kch]);
            acc[0][ct] = __builtin_amdgcn_mfma_f32_16x16x32_bf16(a0, bv, acc[0][ct], 0, 0, 0);
            acc[1][ct] = __builtin_amdgcn_mfma_f32_16x16x32_bf16(a1, bv, acc[1][ct], 0, 0, 0);
        }
        __syncthreads();
    }

    int col16 = lane & 15;
#pragma unroll
    for (int rf = 0; rf < 2; rf++) {
#pragma unroll
        for (int ri = 0; ri < 4; ri++) {
            int lr   = wave * 32 + rf * 16 + (lane >> 4) * 4 + ri;
            bool ok  = (mt * 128 + lr < count);
            int  rr  = rowbase + lr;
            int  pid = ok ? pairid[rr] : 0;
            float gs = ok ? gwr[rr] : 0.f;
#pragma unroll
            for (int ct = 0; ct < 8; ct++) {
                if (ok)
                    outp[(size_t)pid * kH + (n0 + ct * 16 + col16)] = gs * acc[rf][ct][ri];
            }
        }
    }
}

// ---------------------------------------------------------------------------
// Fallback GEMMs (previous verified kernels, used when workspace is small)
// ---------------------------------------------------------------------------
#define BK  32
#define LDK 40

__global__ __launch_bounds__(256) void gemm1_small(
    const float* __restrict__ wsw, const unsigned short* __restrict__ Xg,
    unsigned short* __restrict__ inter,
    const int* __restrict__ cnt, const int* __restrict__ offs)
{
    int e     = blockIdx.z;
    int count = cnt[e];
    int mt    = blockIdx.x;
    if (mt * 64 >= count) return;
    int nt      = blockIdx.y;
    int rowbase = offs[e] + mt * 64;
    int n0      = nt * 64;

    __shared__ unsigned short As[64][LDK];
    __shared__ unsigned short Bs[128][LDK];

    int tid  = threadIdx.x;
    int wave = tid >> 6, lane = tid & 63;

    f32x4 acc[8];
#pragma unroll
    for (int i = 0; i < 8; i++) acc[i] = {0.f, 0.f, 0.f, 0.f};

    const float* wsE = wsw + (size_t)e * k2I * kH;

    int ar = tid >> 2, ac = (tid & 3) * 8;
    int br = tid >> 1, bc = (tid & 1) * 16;
    size_t browg = (br < 64) ? (size_t)(n0 + br) : (size_t)(kI + n0 + (br - 64));
    const float*          bsrc = wsE + browg * kH + bc;
    const unsigned short* asrc = Xg + (size_t)(rowbase + ar) * kH + ac;

    int mrow = wave * 16 + (lane & 15);
    int kch  = (lane >> 4) * 8;

    for (int k0 = 0; k0 < kH; k0 += BK) {
        uint4 av = *(const uint4*)(asrc + k0);
        const float4* bp = (const float4*)(bsrc + k0);
        float4 f0 = bp[0], f1 = bp[1], f2 = bp[2], f3 = bp[3];
        __syncthreads();
        *(uint4*)(&As[ar][ac]) = av;
        *(uint4*)(&Bs[br][bc]) =
            make_uint4(pk2(f0.x, f0.y), pk2(f0.z, f0.w), pk2(f1.x, f1.y), pk2(f1.z, f1.w));
        *(uint4*)(&Bs[br][bc + 8]) =
            make_uint4(pk2(f2.x, f2.y), pk2(f2.z, f2.w), pk2(f3.x, f3.y), pk2(f3.z, f3.w));
        __syncthreads();
        bf16x8 af = *(const bf16x8*)(&As[mrow][kch]);
#pragma unroll
        for (int ct = 0; ct < 8; ct++) {
            bf16x8 bfv = *(const bf16x8*)(&Bs[ct * 16 + (lane & 15)][kch]);
            acc[ct] = __builtin_amdgcn_mfma_f32_16x16x32_bf16(af, bfv, acc[ct], 0, 0, 0);
        }
    }

    int col = lane & 15;
    int lr0 = wave * 16 + (lane >> 4) * 4;
#pragma unroll
    for (int ct = 0; ct < 4; ct++) {
#pragma unroll
        for (int ri = 0; ri < 4; ri++) {
            int lr = lr0 + ri;
            if (mt * 64 + lr < count) {
                float g = acc[ct][ri];
                float u = acc[ct + 4][ri];
                float v = (g / (1.f + __expf(-g))) * u;
                inter[(size_t)(rowbase + lr) * kI + (n0 + ct * 16 + col)] = f2bfu(v);
            }
        }
    }
}

__global__ __launch_bounds__(256) void gemm2_small(
    const float* __restrict__ w2, const unsigned short* __restrict__ inter,
    const int* __restrict__ cnt, const int* __restrict__ offs,
    const int* __restrict__ pairid, const float* __restrict__ gwr,
    float* __restrict__ outp)
{
    int e     = blockIdx.z;
    int count = cnt[e];
    int mt    = blockIdx.x;
    if (mt * 64 >= count) return;
    int nt      = blockIdx.y;
    int rowbase = offs[e] + mt * 64;
    int n0      = nt * 128;

    __shared__ unsigned short As[64][LDK];
    __shared__ unsigned short Bs[128][LDK];

    int tid  = threadIdx.x;
    int wave = tid >> 6, lane = tid & 63;

    f32x4 acc[8];
#pragma unroll
    for (int i = 0; i < 8; i++) acc[i] = {0.f, 0.f, 0.f, 0.f};

    const float* w2E = w2 + (size_t)e * kH * kI;

    int ar = tid >> 2, ac = (tid & 3) * 8;
    int br = tid >> 1, bc = (tid & 1) * 16;
    const float*          bsrc = w2E + (size_t)(n0 + br) * kI + bc;
    const unsigned short* asrc = inter + (size_t)(rowbase + ar) * kI + ac;

    int mrow = wave * 16 + (lane & 15);
    int kch  = (lane >> 4) * 8;

    for (int k0 = 0; k0 < kI; k0 += BK) {
        uint4 av = *(const uint4*)(asrc + k0);
        const float4* bp = (const float4*)(bsrc + k0);
        float4 f0 = bp[0], f1 = bp[1], f2 = bp[2], f3 = bp[3];
        __syncthreads();
        *(uint4*)(&As[ar][ac]) = av;
        *(uint4*)(&Bs[br][bc]) =
            make_uint4(pk2(f0.x, f0.y), pk2(f0.z, f0.w), pk2(f1.x, f1.y), pk2(f1.z, f1.w));
        *(uint4*)(&Bs[br][bc + 8]) =
            make_uint4(pk2(f2.x, f2.y), pk2(f2.z, f2.w), pk2(f3.x, f3.y), pk2(f3.z, f3.w));
        __syncthreads();
        bf16x8 af = *(const bf16x8*)(&As[mrow][kch]);
#pragma unroll
        for (int ct = 0; ct < 8; ct++) {
            bf16x8 bfv = *(const bf16x8*)(&Bs[ct * 16 + (lane & 15)][kch]);
            acc[ct] = __builtin_amdgcn_mfma_f32_16x16x32_bf16(af, bfv, acc[ct], 0, 0, 0);
        }
    }

    int col = lane & 15;
    int lr0 = wave * 16 + (lane >> 4) * 4;
    int  pids[4]; float gs[4]; bool ok[4];
#pragma unroll
    for (int ri = 0; ri < 4; ri++) {
        int lr = lr0 + ri;
        ok[ri]   = (mt * 64 + lr < count);
        int rr   = rowbase + lr;
        pids[ri] = ok[ri] ? pairid[rr] : 0;
        gs[ri]   = ok[ri] ? gwr[rr] : 0.f;
    }
#pragma unroll
    for (int ct = 0; ct < 8; ct++) {
#pragma unroll
        for (int ri = 0; ri < 4; ri++) {
            if (ok[ri]) {
                outp[(size_t)pids[ri] * kH + (n0 + ct * 16 + col)] = gs[ri] * acc[ct][ri];
            }
        }
    }
}

// out[t,h] = outp[2t,h] + outp[2t+1,h]
__global__ __launch_bounds__(256) void combine_kernel(
    const float* __restrict__ outp, float* __restrict__ out)
{
    size_t i = ((size_t)blockIdx.x * 256 + threadIdx.x) * 4;
    size_t t = i >> 11;
    size_t h = i & (kH - 1);
    size_t base = t * 2 * kH + h;
    float4 a = *(const float4*)(outp + base);
    float4 b = *(const float4*)(outp + base + kH);
    float4 r = make_float4(a.x + b.x, a.y + b.y, a.z + b.z, a.w + b.w);
    *(float4*)(out + i) = r;
}

// ---------------------------------------------------------------------------
extern "C" void kernel_launch(void* const* d_in, const int* in_sizes, int n_in,
                              void* d_out, int out_size, void* d_ws, size_t ws_size,
                              hipStream_t stream)
{
    (void)in_sizes; (void)n_in; (void)out_size;
    const float* x   = (const float*)d_in[0];
    const float* gw  = (const float*)d_in[1];
    const float* wsw = (const float*)d_in[2];
    const float* w2  = (const float*)d_in[3];
    float* out = (float*)d_out;

    char* w = (char*)d_ws;
    const size_t MB = 1024 * 1024;
    // workspace layout
    int*   cnt    = (int*)(w + 0);
    int*   cnt2   = (int*)(w + 64);
    int*   offs   = (int*)(w + 128);
    float* gsel   = (float*)(w + 1024);
    int*   sel    = (int*)(w + 20480);
    int*   rowtok = (int*)(w + 40960);
    int*   pairid = (int*)(w + 61440);
    float* gwr    = (float*)(w + 81920);
    unsigned short* Xg    = (unsigned short*)(w + 1 * MB);    // 4224 x 2048 bf16 (128-padded)
    unsigned short* inter = (unsigned short*)(w + 32 * MB);   // 4224 x 4096 bf16
    float*          outp  = (float*)(w + 68 * MB);            // 4096 x 2048 f32
    // bf16 weight copies (fast path only). w2bf aliases wsbf (dead after gemm1).
    unsigned short* wsbf  = (unsigned short*)(w + 112 * MB);  // 8 x 8192 x 2048 bf16 = 256 MiB
    unsigned short* w2bf  = (unsigned short*)(w + 112 * MB);  // 8 x 2048 x 4096 bf16 = 128 MiB

    bool big = ws_size >= ((size_t)368 << 20);

    hipMemsetAsync(w, 0, 128, stream);
    router_kernel <<<kT / 4, 256, 0, stream>>>(x, gw, gsel, sel, cnt);
    offsets_kernel<<<1, 64, 0, stream>>>(cnt, offs);
    scatter_kernel<<<(kT * 2) / 256, 256, 0, stream>>>(gsel, sel, offs, cnt2,
                                                       rowtok, pairid, gwr);
    gather_kernel <<<kT * 2, 256, 0, stream>>>(x, rowtok, Xg);

    if (big) {
        cvt_kernel <<<4096, 256, 0, stream>>>(wsw, wsbf, (size_t)kE * k2I * kH / 8);
        gemm1_big  <<<dim3(32, kI / 64, kE), 256, 0, stream>>>(wsbf, Xg, inter, cnt, offs);
        cvt_kernel <<<2048, 256, 0, stream>>>(w2, w2bf, (size_t)kE * kH * kI / 8);
        gemm2_big  <<<dim3(32, kH / 128, kE), 256, 0, stream>>>(w2bf, inter, cnt, offs,
                                                                pairid, gwr, outp);
    } else {
        gemm1_small<<<dim3(32, kI / 64, kE), 256, 0, stream>>>(wsw, Xg, inter, cnt, offs);
        gemm2_small<<<dim3(32, kH / 128, kE), 256, 0, stream>>>(w2, inter, cnt, offs,
                                                                pairid, gwr, outp);
    }
    combine_kernel<<<(kT * kH) / (4 * 256), 256, 0, stream>>>(outp, out);
}